// Round 25
// baseline (49.820 us; speedup 1.0000x reference)
//
#include <hip/hip_runtime.h>
#include <math.h>

#define CAP 64        // fixed edge slots per node; cnt>CAP takes the (never-hit) fallback
#define CSTRIDE 16    // one counter per 64B L2 line

#define LOG2E    1.44269504088896341f
#define LOG2E_3  0.48089834696298780f   // log2(e)/3

typedef float v2f __attribute__((ext_vector_type(2)));

__device__ __forceinline__ float celu3(float x) {
    return fmaxf(x, 0.0f) + 3.0f * (exp2f(fminf(x, 0.0f) * LOG2E_3) - 1.0f);
}
__device__ __forceinline__ v2f celu2(v2f x) {
    v2f zero = {0.f, 0.f};
    v2f pos = __builtin_elementwise_max(x, zero);
    v2f neg = __builtin_elementwise_min(x, zero);
    v2f targ = neg * LOG2E_3;
    v2f e;
    e.x = exp2f(targ.x);
    e.y = exp2f(targ.y);
    return (pos - 3.0f) + e * 3.0f;
}

template <int CTRL>
__device__ __forceinline__ float dpp_add(float v) {
    int o = __builtin_amdgcn_update_dpp(0, __float_as_int(v), CTRL, 0xf, 0xf, true);
    return v + __int_as_float(o);
}
template <int CTRL>
__device__ __forceinline__ float dpp_mov(float v) {
    int o = __builtin_amdgcn_update_dpp(0, __float_as_int(v), CTRL, 0xf, 0xf, true);
    return __int_as_float(o);
}
__device__ __forceinline__ float red16(float v) {
    v = dpp_add<0xB1>(v);
    v = dpp_add<0x4E>(v);
    v = dpp_add<0x124>(v);
    v = dpp_add<0x128>(v);
    return v;
}
__device__ __forceinline__ float wave_sum64(float v) {
    v = red16(v);
    v += __shfl_xor(v, 16, 64);
    v += __shfl_xor(v, 32, 64);
    return v;
}
// reduce across the 8 row-groups (lane bits 3,4,5)
__device__ __forceinline__ v2f xor_red_g(v2f v) {
    v.x += __shfl_xor(v.x, 8);  v.y += __shfl_xor(v.y, 8);
    v.x += __shfl_xor(v.x, 16); v.y += __shfl_xor(v.y, 16);
    v.x += __shfl_xor(v.x, 32); v.y += __shfl_xor(v.y, 32);
    return v;
}

// ---- K1: zero padded counts + a1 (one launch) ------------------------------

__global__ __launch_bounds__(256) void init_kernel(
    int* __restrict__ counts, int N,
    const float* __restrict__ feat, const float* __restrict__ w1,
    float* __restrict__ a1)
{
    int nz = N * CSTRIDE;
    int nblk_zero = (nz + 255) / 256;
    if ((int)blockIdx.x < nblk_zero) {
        int i = blockIdx.x * 256 + threadIdx.x;
        if (i < nz) counts[i] = 0;
        return;
    }
    int n = (blockIdx.x - nblk_zero) * 4 + (threadIdx.x >> 6);
    int lane = threadIdx.x & 63;
    if (n >= N) return;
    float f = feat[(long)n * 64 + lane];
    float s[4];
#pragma unroll
    for (int h = 0; h < 4; ++h) s[h] = wave_sum64(f * w1[h * 64 + lane]);
    if (lane < 4) a1[n * 4 + lane] = celu3(s[lane]);
}

// ---- K2: hist + direct slot scatter (padded counters) ----------------------

__global__ __launch_bounds__(256) void hist_kernel(
    const int* __restrict__ seg, int* __restrict__ counts,
    int* __restrict__ elist, int E)
{
    int i = blockIdx.x * 256 + threadIdx.x;
    int stride = gridDim.x * 256;
    for (; i < E; i += stride) {
        int s = seg[i];
        int r = atomicAdd(&counts[s * CSTRIDE], 1);
        if (r < CAP) elist[s * CAP + r] = i;
    }
}

// ---- K3: fused, 8 ROWS PER CHUNK (8-lane dim groups) -----------------------
// ONE WAVE PER BLOCK, one node per block. lane = (g8 = row-group 0..7,
// o = dim-octet 0..7 -> dims 8o..8o+7, t = lane&3 = head).
// Per chunk: 8 edges. Reduce = quad xor1+xor2 (dpp) + one shfl_xor(4) on the
// head-selected value. A/p at 2x redundancy (vs 4x in r21). All per-chunk
// machinery amortizes over 2x the edges. meta read exactly once.

__global__ __launch_bounds__(64) void fused_kernel(
    const float* __restrict__ meta, const float* __restrict__ w2,
    const float* __restrict__ a1, const int* __restrict__ counts,
    const int* __restrict__ elist, const int* __restrict__ seg,
    float* __restrict__ out, int N, int E)
{
    int lane = threadIdx.x;
    int n = blockIdx.x;
    if (n >= N) return;

    int cnt = counts[n * CSTRIDE];
    int g8 = lane >> 3;      // row-group (gather) / head (store, g8<4)
    int o  = lane & 7;       // dim-octet
    int t  = lane & 3;       // head in the transposed compute

    if (cnt == 0) {
        if (g8 < 4) {
            long ob = (long)n * 256 + g8 * 64 + o * 8;
            float4 z = {0.f, 0.f, 0.f, 0.f};
            *(float4*)(out + ob) = z;
            *(float4*)(out + ob + 4) = z;
        }
        return;
    }

    float4 a1v = *(const float4*)(a1 + (long)n * 4);

    if (cnt <= CAP) {
        // w2 slices: 4 heads x my 8 dims, as 4 v2f per head
        const float* w2o = w2 + o * 8;
        float4 wA0 = *(const float4*)(w2o + 0 * 64), wB0 = *(const float4*)(w2o + 0 * 64 + 4);
        float4 wA1 = *(const float4*)(w2o + 1 * 64), wB1 = *(const float4*)(w2o + 1 * 64 + 4);
        float4 wA2 = *(const float4*)(w2o + 2 * 64), wB2 = *(const float4*)(w2o + 2 * 64 + 4);
        float4 wA3 = *(const float4*)(w2o + 3 * 64), wB3 = *(const float4*)(w2o + 3 * 64 + 4);
        v2f w0a = {wA0.x, wA0.y}, w0b = {wA0.z, wA0.w}, w0c = {wB0.x, wB0.y}, w0d = {wB0.z, wB0.w};
        v2f w1a = {wA1.x, wA1.y}, w1b = {wA1.z, wA1.w}, w1c = {wB1.x, wB1.y}, w1d = {wB1.z, wB1.w};
        v2f w2a = {wA2.x, wA2.y}, w2b = {wA2.z, wA2.w}, w2c = {wB2.x, wB2.y}, w2d = {wB2.z, wB2.w};
        v2f w3a = {wA3.x, wA3.y}, w3b = {wA3.z, wA3.w}, w3c = {wB3.x, wB3.y}, w3d = {wB3.z, wB3.w};

        float a1sel = (t == 0) ? a1v.x : (t == 1) ? a1v.y : (t == 2) ? a1v.z : a1v.w;

        int eid_l = (lane < cnt) ? elist[n * CAP + lane] : 0;
        const float* meta_o = meta + o * 8;

        float sp = 0.f;
        v2f a0a = {0,0}, a0b = {0,0}, a0c = {0,0}, a0d = {0,0};
        v2f a1a_ = {0,0}, a1b_ = {0,0}, a1c_ = {0,0}, a1d_ = {0,0};
        v2f a2a = {0,0}, a2b = {0,0}, a2c = {0,0}, a2d = {0,0};
        v2f a3a = {0,0}, a3b = {0,0}, a3c = {0,0}, a3d = {0,0};

        int nch = (cnt + 7) >> 3;
#pragma unroll 4
        for (int c = 0; c < nch; ++c) {
            int j = c * 8 + g8;                // my row this chunk (<=63)
            bool vr = j < cnt;
            int eid = __shfl(eid_l, j);
            const float* rp = meta_o + (long)eid * 64;
            float4 va = *(const float4*)rp;
            float4 vb = *(const float4*)(rp + 4);
            v2f e0 = {va.x, va.y}, e1 = {va.z, va.w};
            v2f e2 = {vb.x, vb.y}, e3 = {vb.z, vb.w};
            e0 = celu2(e0); e1 = celu2(e1); e2 = celu2(e2); e3 = celu2(e3);

            // partial dots over my 8 dims, 4 heads
            v2f pd0 = e0 * w0a + e1 * w0b + e2 * w0c + e3 * w0d;
            v2f pd1 = e0 * w1a + e1 * w1b + e2 * w1c + e3 * w1d;
            v2f pd2 = e0 * w2a + e1 * w2b + e2 * w2c + e3 * w2d;
            v2f pd3 = e0 * w3a + e1 * w3b + e2 * w3c + e3 * w3d;
            float d0 = pd0.x + pd0.y;
            float d1 = pd1.x + pd1.y;
            float d2 = pd2.x + pd2.y;
            float d3 = pd3.x + pd3.y;

            // quad sums (xor1, xor2), then finish ONLY my head t with one xor4
            d0 = dpp_add<0xB1>(d0); d1 = dpp_add<0xB1>(d1);
            d2 = dpp_add<0xB1>(d2); d3 = dpp_add<0xB1>(d3);
            d0 = dpp_add<0x4E>(d0); d1 = dpp_add<0x4E>(d1);
            d2 = dpp_add<0x4E>(d2); d3 = dpp_add<0x4E>(d3);
            float dsel = (t == 0) ? d0 : (t == 1) ? d1 : (t == 2) ? d2 : d3;
            dsel += __shfl_xor(dsel, 4, 64);   // cross-quad within the 8-lane group

            float A = vr ? celu3(a1sel + dsel) : -INFINITY;
            float p = exp2f(fminf(A, 80.f) * LOG2E);
            sp += p;

            // all 4 head-p values live in every quad (t = lane&3 in both quads)
            float b0 = dpp_mov<0x00>(p);
            float b1 = dpp_mov<0x55>(p);
            float b2 = dpp_mov<0xAA>(p);
            float b3 = dpp_mov<0xFF>(p);

            a0a += e0 * b0; a0b += e1 * b0; a0c += e2 * b0; a0d += e3 * b0;
            a1a_ += e0 * b1; a1b_ += e1 * b1; a1c_ += e2 * b1; a1d_ += e3 * b1;
            a2a += e0 * b2; a2b += e1 * b2; a2c += e2 * b2; a2d += e3 * b2;
            a3a += e0 * b3; a3b += e1 * b3; a3c += e2 * b3; a3d += e3 * b3;
        }

        // sp: lanes l and l^4 duplicate (row,head) values; xor8/16/32 only mixes
        // groups (bits 3-5) so each group's rows count exactly once.
        sp += __shfl_xor(sp, 8); sp += __shfl_xor(sp, 16); sp += __shfl_xor(sp, 32);

        // acc: reduce across the 8 row-groups; lanes l,l^4 hold different dims.
        a0a = xor_red_g(a0a); a0b = xor_red_g(a0b); a0c = xor_red_g(a0c); a0d = xor_red_g(a0d);
        a1a_ = xor_red_g(a1a_); a1b_ = xor_red_g(a1b_); a1c_ = xor_red_g(a1c_); a1d_ = xor_red_g(a1d_);
        a2a = xor_red_g(a2a); a2b = xor_red_g(a2b); a2c = xor_red_g(a2c); a2d = xor_red_g(a2d);
        a3a = xor_red_g(a3a); a3b = xor_red_g(a3b); a3c = xor_red_g(a3c); a3d = xor_red_g(a3d);

        // denominators for all 4 heads, from sp (head t) via quad broadcast
        float dd0 = dpp_mov<0x00>(sp);
        float dd1 = dpp_mov<0x55>(sp);
        float dd2 = dpp_mov<0xAA>(sp);
        float dd3 = dpp_mov<0xFF>(sp);

        if (g8 < 4) {   // group g8 stores head g8, dims 8o..8o+7
            float dsel2 = (g8 == 0) ? dd0 : (g8 == 1) ? dd1 : (g8 == 2) ? dd2 : dd3;
            float rg = 1.f / dsel2;
            v2f r0 = (g8 == 0) ? a0a : (g8 == 1) ? a1a_ : (g8 == 2) ? a2a : a3a;
            v2f r1 = (g8 == 0) ? a0b : (g8 == 1) ? a1b_ : (g8 == 2) ? a2b : a3b;
            v2f r2 = (g8 == 0) ? a0c : (g8 == 1) ? a1c_ : (g8 == 2) ? a2c : a3c;
            v2f r3 = (g8 == 0) ? a0d : (g8 == 1) ? a1d_ : (g8 == 2) ? a2d : a3d;
            long ob = (long)n * 256 + g8 * 64 + o * 8;
            float4 oA, oB;
            oA.x = celu3(r0.x * rg); oA.y = celu3(r0.y * rg);
            oA.z = celu3(r1.x * rg); oA.w = celu3(r1.y * rg);
            oB.x = celu3(r2.x * rg); oB.y = celu3(r2.y * rg);
            oB.z = celu3(r3.x * rg); oB.w = celu3(r3.y * rg);
            *(float4*)(out + ob) = oA;
            *(float4*)(out + ob + 4) = oB;
        }
        return;
    }

    // ---- fallback (cnt > CAP): brute-force seg scan, lane = dim. correct, never hot
    {
        float a10 = a1v.x, a11 = a1v.y, a12 = a1v.z, a13 = a1v.w;
        float w2v0 = w2[0 * 64 + lane], w2v1 = w2[1 * 64 + lane];
        float w2v2 = w2[2 * 64 + lane], w2v3 = w2[3 * 64 + lane];
        float m0 = -INFINITY, m1 = -INFINITY, m2 = -INFINITY, m3 = -INFINITY;
        float s0 = 0.f, s1 = 0.f, s2 = 0.f, s3 = 0.f;
        float ac0 = 0.f, ac1 = 0.f, ac2 = 0.f, ac3 = 0.f;
        for (int base = 0; base < E; base += 64) {
            int e = base + lane;
            bool hit = (e < E) && (seg[e] == n);
            unsigned long long ball = __ballot(hit);
            while (ball) {
                int b = __ffsll((long long)ball) - 1;
                ball &= ball - 1;
                int eid = base + b;
                float eft = celu3(meta[(long)eid * 64 + lane]);
                float d0 = wave_sum64(eft * w2v0);
                float d1 = wave_sum64(eft * w2v1);
                float d2 = wave_sum64(eft * w2v2);
                float d3 = wave_sum64(eft * w2v3);
                float A0 = celu3(a10 + d0), A1 = celu3(a11 + d1);
                float A2 = celu3(a12 + d2), A3 = celu3(a13 + d3);
                float nm0 = fmaxf(m0, A0), nm1 = fmaxf(m1, A1);
                float nm2 = fmaxf(m2, A2), nm3 = fmaxf(m3, A3);
                float al0 = __expf(m0 - nm0), al1 = __expf(m1 - nm1);
                float al2 = __expf(m2 - nm2), al3 = __expf(m3 - nm3);
                float p0 = __expf(A0 - nm0), p1 = __expf(A1 - nm1);
                float p2 = __expf(A2 - nm2), p3 = __expf(A3 - nm3);
                s0 = fmaf(al0, s0, p0); s1 = fmaf(al1, s1, p1);
                s2 = fmaf(al2, s2, p2); s3 = fmaf(al3, s3, p3);
                ac0 = fmaf(p0, eft, al0 * ac0); ac1 = fmaf(p1, eft, al1 * ac1);
                ac2 = fmaf(p2, eft, al2 * ac2); ac3 = fmaf(p3, eft, al3 * ac3);
                m0 = nm0; m1 = nm1; m2 = nm2; m3 = nm3;
            }
        }
        long ob2 = (long)n * 256 + lane;
        out[ob2]       = celu3(ac0 / s0);
        out[ob2 + 64]  = celu3(ac1 / s1);
        out[ob2 + 128] = celu3(ac2 / s2);
        out[ob2 + 192] = celu3(ac3 / s3);
    }
}

// ---- launch ----------------------------------------------------------------

extern "C" void kernel_launch(void* const* d_in, const int* in_sizes, int n_in,
                              void* d_out, int out_size, void* d_ws, size_t ws_size,
                              hipStream_t stream)
{
    const float* feat = (const float*)d_in[0];
    const float* meta = (const float*)d_in[1];
    const float* w1   = (const float*)d_in[2];
    const float* w2   = (const float*)d_in[3];
    const int*   seg  = (const int*)d_in[4];
    float* out = (float*)d_out;

    int N = in_sizes[0] / 64;
    int E = in_sizes[4];

    float* a1   = (float*)d_ws;                    // N*4 floats
    int* counts = (int*)(a1 + (size_t)N * 4);      // N*CSTRIDE ints (padded)
    int* elist  = counts + (size_t)N * CSTRIDE;    // N*CAP ints

    int nblk_zero = (N * CSTRIDE + 255) / 256;
    int nblk_a1   = (N + 3) / 4;

    init_kernel<<<nblk_zero + nblk_a1, 256, 0, stream>>>(counts, N, feat, w1, a1);
    hist_kernel<<<512, 256, 0, stream>>>(seg, counts, elist, E);
    fused_kernel<<<N, 64, 0, stream>>>(meta, w2, a1, counts, elist, seg, out, N, E);
}

// Round 26
// 44.847 us; speedup vs baseline: 1.1109x; 1.1109x over previous
//
#include <hip/hip_runtime.h>
#include <math.h>

#define CAP 64        // fixed edge slots per node; cnt>CAP takes the (never-hit) fallback
#define CSTRIDE 16    // one counter per 64B L2 line

#define LOG2E    1.44269504088896341f
#define LOG2E_3  0.48089834696298780f   // log2(e)/3

typedef float v2f __attribute__((ext_vector_type(2)));

__device__ __forceinline__ float celu3(float x) {
    // celu(x,3) = max(x,0) + 3*(2^(min(x,0)*log2e/3) - 1); exp2f = native v_exp_f32
    return fmaxf(x, 0.0f) + 3.0f * (exp2f(fminf(x, 0.0f) * LOG2E_3) - 1.0f);
}

// packed celu on 2 floats: max/min/mul/fma lower to v_pk_* on gfx950
__device__ __forceinline__ v2f celu2(v2f x) {
    v2f zero = {0.f, 0.f};
    v2f pos = __builtin_elementwise_max(x, zero);
    v2f neg = __builtin_elementwise_min(x, zero);
    v2f targ = neg * LOG2E_3;                 // v_pk_mul_f32
    v2f e;
    e.x = exp2f(targ.x);                      // scalar transcendental (not packable)
    e.y = exp2f(targ.y);
    return (pos - 3.0f) + e * 3.0f;           // v_pk_add + v_pk_fma
}

// DPP helpers: pure VALU, no LDS pipe on the chain. ctrl must be immediate.
template <int CTRL>
__device__ __forceinline__ float dpp_add(float v) {
    int o = __builtin_amdgcn_update_dpp(0, __float_as_int(v), CTRL, 0xf, 0xf, true);
    return v + __int_as_float(o);
}
template <int CTRL>
__device__ __forceinline__ float dpp_mov(float v) {
    int o = __builtin_amdgcn_update_dpp(0, __float_as_int(v), CTRL, 0xf, 0xf, true);
    return __int_as_float(o);
}
__device__ __forceinline__ float red16(float v) {
    v = dpp_add<0xB1>(v);    // quad_perm xor1
    v = dpp_add<0x4E>(v);    // quad_perm xor2
    v = dpp_add<0x124>(v);   // row_ror:4
    v = dpp_add<0x128>(v);   // row_ror:8
    return v;
}
__device__ __forceinline__ float wave_sum64(float v) {
    v = red16(v);
    v += __shfl_xor(v, 16, 64);
    v += __shfl_xor(v, 32, 64);
    return v;
}
__device__ __forceinline__ v2f xor_red2(v2f v) {
    v.x += __shfl_xor(v.x, 16); v.x += __shfl_xor(v.x, 32);
    v.y += __shfl_xor(v.y, 16); v.y += __shfl_xor(v.y, 32);
    return v;
}

// ---- K1: zero padded counts + a1 (one launch) ------------------------------

__global__ __launch_bounds__(256) void init_kernel(
    int* __restrict__ counts, int N,
    const float* __restrict__ feat, const float* __restrict__ w1,
    float* __restrict__ a1)
{
    int nz = N * CSTRIDE;
    int nblk_zero = (nz + 255) / 256;
    if ((int)blockIdx.x < nblk_zero) {
        int i = blockIdx.x * 256 + threadIdx.x;
        if (i < nz) counts[i] = 0;
        return;
    }
    int n = (blockIdx.x - nblk_zero) * 4 + (threadIdx.x >> 6);
    int lane = threadIdx.x & 63;
    if (n >= N) return;
    float f = feat[(long)n * 64 + lane];
    float s[4];
#pragma unroll
    for (int h = 0; h < 4; ++h) s[h] = wave_sum64(f * w1[h * 64 + lane]);
    if (lane < 4) a1[n * 4 + lane] = celu3(s[lane]);
}

// ---- K2: hist + direct slot scatter (padded counters) ----------------------

__global__ __launch_bounds__(256) void hist_kernel(
    const int* __restrict__ seg, int* __restrict__ counts,
    int* __restrict__ elist, int E)
{
    int i = blockIdx.x * 256 + threadIdx.x;
    int stride = gridDim.x * 256;
    for (; i < E; i += stride) {
        int s = seg[i];
        int r = atomicAdd(&counts[s * CSTRIDE], 1);
        if (r < CAP) elist[s * CAP + r] = i;
    }
}

// ---- K3: fused dots + fixed-shift softmax + aggregate ----------------------
// ONE WAVE PER BLOCK, one node per block. lane = (g = row-group, q = dim-quad,
// t = quad position = head). TRANSPOSED A/p (r18) + PACKED fp32 math (v_pk_*):
// celu/partial-dot/acc blocks run as 2-wide packed ops. meta read exactly once.

__global__ __launch_bounds__(64) void fused_kernel(
    const float* __restrict__ meta, const float* __restrict__ w2,
    const float* __restrict__ a1, const int* __restrict__ counts,
    const int* __restrict__ elist, const int* __restrict__ seg,
    float* __restrict__ out, int N, int E)
{
    int lane = threadIdx.x;
    int n = blockIdx.x;
    if (n >= N) return;

    int cnt = counts[n * CSTRIDE];
    int g = lane >> 4;       // row-group (gather) / head (store)
    int q = lane & 15;       // dim-quad
    int t = lane & 3;        // quad position = my head in the transposed compute
    long ob = (long)n * 256 + g * 64 + q * 4;

    if (cnt == 0) {
        float4 z = {0.f, 0.f, 0.f, 0.f};
        *(float4*)(out + ob) = z;
        return;
    }

    float4 a1v = *(const float4*)(a1 + (long)n * 4);

    if (cnt <= CAP) {
        // per-lane w2 slice as packed pairs: head h, dims 4q..4q+3
        float4 w0 = *(const float4*)(w2 + 0 * 64 + q * 4);
        float4 w1v = *(const float4*)(w2 + 1 * 64 + q * 4);
        float4 wv2 = *(const float4*)(w2 + 2 * 64 + q * 4);
        float4 w3 = *(const float4*)(w2 + 3 * 64 + q * 4);
        v2f w0a = {w0.x, w0.y},  w0b = {w0.z, w0.w};
        v2f w1a = {w1v.x, w1v.y}, w1b = {w1v.z, w1v.w};
        v2f w2a = {wv2.x, wv2.y}, w2b = {wv2.z, wv2.w};
        v2f w3a = {w3.x, w3.y},  w3b = {w3.z, w3.w};

        // hoisted: my head's a1
        float a1sel = (t == 0) ? a1v.x : (t == 1) ? a1v.y : (t == 2) ? a1v.z : a1v.w;

        int eid_l = (lane < cnt) ? elist[n * CAP + lane] : 0;
        const float* meta_q = meta + q * 4;

        float sp = 0.f;   // head-t partial denominator (per group)
        v2f acc0a = {0,0}, acc0b = {0,0}, acc1a = {0,0}, acc1b = {0,0};
        v2f acc2a = {0,0}, acc2b = {0,0}, acc3a = {0,0}, acc3b = {0,0};

        int nch = (cnt + 3) >> 2;
#pragma unroll 8
        for (int c = 0; c < nch; ++c) {
            int j = c * 4 + g;                 // my row this chunk (<=63)
            bool vr = j < cnt;
            int eid = __shfl(eid_l, j);
            float4 v = *(const float4*)(meta_q + (long)eid * 64);
            v2f va = {v.x, v.y}, vb = {v.z, v.w};
            v2f efa = celu2(va), efb = celu2(vb);

            // partial dots (packed), then horizontal add
            v2f pd0 = efa * w0a + efb * w0b;   // 2x v_pk ops
            v2f pd1 = efa * w1a + efb * w1b;
            v2f pd2 = efa * w2a + efb * w2b;
            v2f pd3 = efa * w3a + efb * w3b;
            float d0 = pd0.x + pd0.y;
            float d1 = pd1.x + pd1.y;
            float d2 = pd2.x + pd2.y;
            float d3 = pd3.x + pd3.y;

            // quad-level sums for all heads, then finish ONLY my head t
            d0 = dpp_add<0xB1>(d0); d1 = dpp_add<0xB1>(d1);
            d2 = dpp_add<0xB1>(d2); d3 = dpp_add<0xB1>(d3);
            d0 = dpp_add<0x4E>(d0); d1 = dpp_add<0x4E>(d1);
            d2 = dpp_add<0x4E>(d2); d3 = dpp_add<0x4E>(d3);
            float dsel = (t == 0) ? d0 : (t == 1) ? d1 : (t == 2) ? d2 : d3;
            dsel = dpp_add<0x124>(dsel);       // row_ror:4
            dsel = dpp_add<0x128>(dsel);       // row_ror:8 -> full 64-dim dot, head t

            // A/p once per lane (head t); p = 0 for invalid rows (exp2(-inf)=0)
            float A = vr ? celu3(a1sel + dsel) : -INFINITY;
            float p = exp2f(fminf(A, 80.f) * LOG2E);
            sp += p;

            // broadcast quad's 4 head-p values to all quad lanes
            float b0 = dpp_mov<0x00>(p);
            float b1 = dpp_mov<0x55>(p);
            float b2 = dpp_mov<0xAA>(p);
            float b3 = dpp_mov<0xFF>(p);

            // packed accumulate: 8 v_pk_fma vs 16 scalar fma
            acc0a += efa * b0; acc0b += efb * b0;
            acc1a += efa * b1; acc1b += efb * b1;
            acc2a += efa * b2; acc2b += efb * b2;
            acc3a += efa * b3; acc3b += efb * b3;
        }

        // sp: within a group, same-t lanes hold identical values; sum across groups
        sp += __shfl_xor(sp, 16); sp += __shfl_xor(sp, 32);

        // acc reduce across row-groups (xor 16, 32)
        acc0a = xor_red2(acc0a); acc0b = xor_red2(acc0b);
        acc1a = xor_red2(acc1a); acc1b = xor_red2(acc1b);
        acc2a = xor_red2(acc2a); acc2b = xor_red2(acc2b);
        acc3a = xor_red2(acc3a); acc3b = xor_red2(acc3b);

        float rg = 1.f / __int_as_float(__builtin_amdgcn_ds_bpermute(g << 2, __float_as_int(sp)));

        v2f ava = (g == 0) ? acc0a : (g == 1) ? acc1a : (g == 2) ? acc2a : acc3a;
        v2f avb = (g == 0) ? acc0b : (g == 1) ? acc1b : (g == 2) ? acc2b : acc3b;
        float4 o;
        o.x = celu3(ava.x * rg); o.y = celu3(ava.y * rg);
        o.z = celu3(avb.x * rg); o.w = celu3(avb.y * rg);
        *(float4*)(out + ob) = o;
        return;
    }

    // ---- fallback (cnt > CAP): brute-force seg scan, lane = dim. correct, never hot
    {
        float a10 = a1v.x, a11 = a1v.y, a12 = a1v.z, a13 = a1v.w;
        float w2v0 = w2[0 * 64 + lane], w2v1 = w2[1 * 64 + lane];
        float w2v2 = w2[2 * 64 + lane], w2v3 = w2[3 * 64 + lane];
        float m0 = -INFINITY, m1 = -INFINITY, m2 = -INFINITY, m3 = -INFINITY;
        float s0 = 0.f, s1 = 0.f, s2 = 0.f, s3 = 0.f;
        float ac0 = 0.f, ac1 = 0.f, ac2 = 0.f, ac3 = 0.f;
        for (int base = 0; base < E; base += 64) {
            int e = base + lane;
            bool hit = (e < E) && (seg[e] == n);
            unsigned long long ball = __ballot(hit);
            while (ball) {
                int b = __ffsll((long long)ball) - 1;
                ball &= ball - 1;
                int eid = base + b;
                float eft = celu3(meta[(long)eid * 64 + lane]);
                float d0 = wave_sum64(eft * w2v0);
                float d1 = wave_sum64(eft * w2v1);
                float d2 = wave_sum64(eft * w2v2);
                float d3 = wave_sum64(eft * w2v3);
                float A0 = celu3(a10 + d0), A1 = celu3(a11 + d1);
                float A2 = celu3(a12 + d2), A3 = celu3(a13 + d3);
                float nm0 = fmaxf(m0, A0), nm1 = fmaxf(m1, A1);
                float nm2 = fmaxf(m2, A2), nm3 = fmaxf(m3, A3);
                float al0 = __expf(m0 - nm0), al1 = __expf(m1 - nm1);
                float al2 = __expf(m2 - nm2), al3 = __expf(m3 - nm3);
                float p0 = __expf(A0 - nm0), p1 = __expf(A1 - nm1);
                float p2 = __expf(A2 - nm2), p3 = __expf(A3 - nm3);
                s0 = fmaf(al0, s0, p0); s1 = fmaf(al1, s1, p1);
                s2 = fmaf(al2, s2, p2); s3 = fmaf(al3, s3, p3);
                ac0 = fmaf(p0, eft, al0 * ac0); ac1 = fmaf(p1, eft, al1 * ac1);
                ac2 = fmaf(p2, eft, al2 * ac2); ac3 = fmaf(p3, eft, al3 * ac3);
                m0 = nm0; m1 = nm1; m2 = nm2; m3 = nm3;
            }
        }
        long ob2 = (long)n * 256 + lane;
        out[ob2]       = celu3(ac0 / s0);
        out[ob2 + 64]  = celu3(ac1 / s1);
        out[ob2 + 128] = celu3(ac2 / s2);
        out[ob2 + 192] = celu3(ac3 / s3);
    }
}

// ---- launch ----------------------------------------------------------------

extern "C" void kernel_launch(void* const* d_in, const int* in_sizes, int n_in,
                              void* d_out, int out_size, void* d_ws, size_t ws_size,
                              hipStream_t stream)
{
    const float* feat = (const float*)d_in[0];
    const float* meta = (const float*)d_in[1];
    const float* w1   = (const float*)d_in[2];
    const float* w2   = (const float*)d_in[3];
    const int*   seg  = (const int*)d_in[4];
    float* out = (float*)d_out;

    int N = in_sizes[0] / 64;
    int E = in_sizes[4];

    float* a1   = (float*)d_ws;                    // N*4 floats
    int* counts = (int*)(a1 + (size_t)N * 4);      // N*CSTRIDE ints (padded)
    int* elist  = counts + (size_t)N * CSTRIDE;    // N*CAP ints

    int nblk_zero = (N * CSTRIDE + 255) / 256;
    int nblk_a1   = (N + 3) / 4;

    init_kernel<<<nblk_zero + nblk_a1, 256, 0, stream>>>(counts, N, feat, w1, a1);
    hist_kernel<<<512, 256, 0, stream>>>(seg, counts, elist, E);
    fused_kernel<<<N, 64, 0, stream>>>(meta, w2, a1, counts, elist, seg, out, N, E);
}